// Round 16
// baseline (50.031 us; speedup 1.0000x reference)
//
#include <hip/hip_runtime.h>

#define HH 128
#define WW 128
#define CC 64
#define KD 16
#define HW (HH * WW)
#define HWB (HW * 4)
#define TOTBYTES (4u * CC * HW * 4u)   // B=4 * C=64 * H*W * 4B = 16.78 MB
#define OOB_SENT 0x40000000            // always-OOB voffset -> HW returns 0

typedef __attribute__((ext_vector_type(4))) int   int32x4_t;
typedef __attribute__((ext_vector_type(4))) float floatx4;
typedef __attribute__((ext_vector_type(2))) float floatx2;

__device__ floatx4 llvm_amdgcn_raw_buffer_load_v4f32(int32x4_t srsrc, int voffset,
                                                     int soffset, int aux)
    __asm("llvm.amdgcn.raw.buffer.load.v4f32");
__device__ floatx2 llvm_amdgcn_raw_buffer_load_v2f32(int32x4_t srsrc, int voffset,
                                                     int soffset, int aux)
    __asm("llvm.amdgcn.raw.buffer.load.v2f32");

__device__ inline int32x4_t make_srd(const void* p, unsigned bytes) {
    const unsigned long long a = (unsigned long long)p;
    int32x4_t r;
    r.x = (int)(a & 0xffffffffull);
    r.y = (int)(a >> 32);
    r.z = (int)bytes;
    r.w = 0x00020000;
    return r;
}

#if __has_builtin(__builtin_amdgcn_exp2f)
#define FAST_EXP2(x) __builtin_amdgcn_exp2f(x)
#define KLOG2E 1.44269504088896340736f
#else
#define FAST_EXP2(x) __expf(x)
#define KLOG2E 1.0f
#endif

// ---- pre-kernel: repack Wk [16][64][9] -> wsr [(c*9+t)*16 + d] -------------
__global__ __launch_bounds__(512, 1) void repack_wk(const float* __restrict__ Wk,
                                                    float* __restrict__ wsr) {
    const int e = blockIdx.x * 512 + threadIdx.x;    // 9216 total
    const int d = e & 15;
    const int r = e >> 4;
    const int t = r % 9;
    const int c = r / 9;
    wsr[e] = Wk[(d * CC + c) * 9 + t];
}

// ============ KERNEL A: k-conv only, high occupancy =========================
// 16(w) x 4(h) tile, 512 thr = 8 waves x 8 channels, 1 px/lane.
// LDS 32 KB partials -> 8-way reduce -> k[b][d][pix] to workspace.
// launch_bounds(512,8): VGPR<=64 -> 4 blocks/CU = 32 waves/CU (grid 1024).
__global__ __launch_bounds__(512, 8) void kconv(
    const float* __restrict__ x, const float* __restrict__ wsr,
    const float* __restrict__ bk, float* __restrict__ kout)
{
    __shared__ float lds[8 * KD * 64];   // 32 KB

    const int tid  = threadIdx.x;
    const int g    = __builtin_amdgcn_readfirstlane(tid >> 6);
    const int lane = tid & 63;
    const int px   = lane & 15, py = lane >> 4;
    const int b    = blockIdx.z;
    const int h    = blockIdx.y * 4 + py;
    const int w    = blockIdx.x * 16 + px;

    const int32x4_t rx = make_srd(x, TOTBYTES);

    const int colb = (w > 0 ? w - 1 : 0) * 4;
    int rowB[3];
#pragma unroll
    for (int r = 0; r < 3; ++r) {
        const int rr = h - 1 + r;
        rowB[r] = (rr >= 0 && rr < HH) ? rr * WW * 4 + colb : OOB_SENT;
    }
    const float mL = (w > 0) ? 1.f : 0.f;
    const float mR = (w < WW - 1) ? 1.f : 0.f;
    const bool  w0e = (w == 0);

    const int base = b * CC * HWB;
    const int c0   = __builtin_amdgcn_readfirstlane(g * 8);

    floatx2 a[8];                        // d-pairs (2i, 2i+1)
#pragma unroll
    for (int i = 0; i < 8; ++i) a[i] = (floatx2){0.f, 0.f};

    auto load3 = [&](floatx4 (&f)[3], int so) {
#pragma unroll
        for (int r = 0; r < 3; ++r)
            f[r] = llvm_amdgcn_raw_buffer_load_v4f32(rx, rowB[r], so, 0);
    };
    auto compute = [&](const floatx4 (&f)[3], const float* wp) {
        float tp[9];
#pragma unroll
        for (int r = 0; r < 3; ++r) {
            tp[r * 3 + 0] = f[r].x * mL;
            tp[r * 3 + 1] = w0e ? f[r].x : f[r].y;
            tp[r * 3 + 2] = (w0e ? f[r].y : f[r].z) * mR;
        }
#pragma unroll
        for (int t = 0; t < 9; ++t) {
            const floatx2 t2 = {tp[t], tp[t]};
#pragma unroll
            for (int j = 0; j < 4; ++j) {          // uniform -> s_load (SMEM pipe)
                const floatx4 w4 = *(const floatx4*)&wp[t * 16 + j * 4];
                const floatx2 lo = __builtin_shufflevector(w4, w4, 0, 1);
                const floatx2 hi = __builtin_shufflevector(w4, w4, 2, 3);
                a[2 * j + 0] = __builtin_elementwise_fma(lo, t2, a[2 * j + 0]);
                a[2 * j + 1] = __builtin_elementwise_fma(hi, t2, a[2 * j + 1]);
            }
        }
    };

    {
        floatx4 f0[3], f1[3];
        load3(f0, base + c0 * HWB);
#pragma unroll
        for (int cp = 0; cp < 4; ++cp) {
            load3(f1, base + (c0 + 2 * cp + 1) * HWB);
            compute(f0, wsr + (c0 + 2 * cp) * 144);
            load3(f0, base + (c0 + 2 * cp + 2) * HWB);   // tail SRD-bounded -> 0
            compute(f1, wsr + (c0 + 2 * cp + 1) * 144);
        }
    }

#pragma unroll
    for (int i = 0; i < 8; ++i) {
        lds[g * 1024 + (2 * i + 0) * 64 + lane] = a[i].x;
        lds[g * 1024 + (2 * i + 1) * 64 + lane] = a[i].y;
    }
    __syncthreads();

#pragma unroll
    for (int rep = 0; rep < 2; ++rep) {
        const int idx = tid + rep * 512;             // = d*64 + pxl
        float s = lds[idx];
#pragma unroll
        for (int gg = 1; gg < 8; ++gg) s += lds[gg * 1024 + idx];
        const int d   = idx >> 6;                    // wave-uniform
        const int pxl = idx & 63;
        const int hh  = blockIdx.y * 4 + (pxl >> 4);
        const int ww  = blockIdx.x * 16 + (pxl & 15);
        kout[(b * KD + d) * HW + hh * WW + ww] =
            fmaxf(s + bk[d], 0.f) * KLOG2E;
    }
}

// ============ KERNEL B: attention only, barrier-free after 4KB k stage ======
// 32(w) x 4(h) tile, 512 thr = 8 waves x 8 channels, 2-px lanes (R12 phase 2).
__global__ __launch_bounds__(512, 4) void attn(
    const float* __restrict__ y, const float* __restrict__ z,
    const float* __restrict__ kout,
    const float* __restrict__ Wq, const float* __restrict__ bq,
    const float* __restrict__ wv, const float* __restrict__ bv,
    float* __restrict__ out)
{
    __shared__ float klds[KD * 128];   // 8 KB

    const int tid  = threadIdx.x;
    const int g    = __builtin_amdgcn_readfirstlane(tid >> 6);
    const int lane = tid & 63;
    const int px16 = lane & 15, py = lane >> 4;
    const int b    = blockIdx.z;
    const int w0b  = blockIdx.x * 32;
    const int h0   = blockIdx.y * 4;
    const int w0   = w0b + px16 * 2;
    const int h    = h0 + py;
    const int pix  = h * WW + w0;
    const int p0   = py * 32 + px16 * 2;

    const int32x4_t ry = make_srd(y, TOTBYTES);
    const int32x4_t rz = make_srd(z, TOTBYTES);

    // stage k tile: 2048 floats, coalesced 128B rows
#pragma unroll
    for (int rep = 0; rep < 4; ++rep) {
        const int idx = tid + rep * 512;             // d*128 + p
        const int d   = idx >> 7;
        const int p   = idx & 127;
        const int row = p >> 5, col = p & 31;
        klds[idx] = kout[(b * KD + d) * HW + (h0 + row) * WW + w0b + col];
    }
    __syncthreads();

    const int colb = (w0 > 0 ? w0 - 1 : 0) * 4;
    int rowB[3];
#pragma unroll
    for (int r = 0; r < 3; ++r) {
        const int rr = h - 1 + r;
        rowB[r] = (rr >= 0 && rr < HH) ? rr * WW * 4 + colb : OOB_SENT;
    }
    const bool  intw = (blockIdx.x > 0) & (blockIdx.x < (WW / 32 - 1));
    const float mL = (w0 > 0) ? 1.f : 0.f;
    const float mR = (w0 + 2 < WW) ? 1.f : 0.f;
    const bool  w0e = (w0 == 0);

    const int base = b * CC * HWB;
    const int c0   = __builtin_amdgcn_readfirstlane(g * 8);

    auto mktaps = [&](const floatx4& f, float (&s)[4]) {
        if (intw) { s[0] = f.x; s[1] = f.y; s[2] = f.z; s[3] = f.w; }
        else {
            s[0] = f.x * mL;
            s[1] = w0e ? f.x : f.y;
            s[2] = w0e ? f.y : f.z;
            s[3] = (w0e ? f.z : f.w) * mR;
        }
    };

    floatx2 kl2[16];
#pragma unroll
    for (int d = 0; d < KD; ++d)
        kl2[d] = *(const floatx2*)&klds[d * 128 + p0];

    auto process = [&](const floatx4 (&f)[3], floatx2 z2, int c) {
        const float* wq = Wq + c * 9;                // uniform -> s_load
        float s[3][4];
#pragma unroll
        for (int r = 0; r < 3; ++r) mktaps(f[r], s[r]);
        floatx2 q2 = {bq[c], bq[c]};
#pragma unroll
        for (int t = 0; t < 9; ++t) {
            const int tr = t / 3, tc = t % 3;
            const floatx2 tp2 = {s[tr][tc], s[tr][tc + 1]};
            const floatx2 wq2 = {wq[t], wq[t]};
            q2 = __builtin_elementwise_fma(wq2, tp2, q2);
        }
        const floatx2 zero2 = {0.f, 0.f};
        q2 = __builtin_elementwise_max(q2, zero2);

        floatx2 num2 = zero2, den2 = zero2;
#pragma unroll
        for (int d = 0; d < KD; ++d) {
            const floatx2 s2 = q2 * kl2[d];          // v_pk_mul_f32
            floatx2 e2;
            e2.x = FAST_EXP2(s2.x);
            e2.y = FAST_EXP2(s2.y);
            const floatx2 wv2 = {wv[d], wv[d]};
            const floatx2 bv2 = {bv[d], bv[d]};
            const floatx2 v2 = __builtin_elementwise_max(
                __builtin_elementwise_fma(z2, wv2, bv2), zero2);
            num2 = __builtin_elementwise_fma(e2, v2, num2);
            den2 = den2 + e2;
        }
        floatx2 o2;
        o2.x = __fdividef(num2.x, den2.x);
        o2.y = __fdividef(num2.y, den2.y);
        *(floatx2*)&out[(size_t)b * CC * HW + (size_t)c * HW + pix] = o2;
    };

    auto load3y = [&](floatx4 (&f)[3], floatx2& zz, int so) {
#pragma unroll
        for (int r = 0; r < 3; ++r)
            f[r] = llvm_amdgcn_raw_buffer_load_v4f32(ry, rowB[r], so, 0);
        zz = llvm_amdgcn_raw_buffer_load_v2f32(rz, pix * 4, so, 0);
    };

    {
        floatx4 fy0[3], fy1[3];
        floatx2 z0, z1;
        load3y(fy0, z0, base + c0 * HWB);
#pragma unroll
        for (int cp = 0; cp < 4; ++cp) {
            load3y(fy1, z1, base + (c0 + 2 * cp + 1) * HWB);
            process(fy0, z0, c0 + 2 * cp);
            load3y(fy0, z0, base + (c0 + 2 * cp + 2) * HWB); // tail SRD-bounded
            process(fy1, z1, c0 + 2 * cp + 1);
        }
    }
}

// ============ fallback: R12-style fused kernel (ws too small for k) =========
__global__ __launch_bounds__(512, 4) void gatev_fused(
    const float* __restrict__ x, const float* __restrict__ y,
    const float* __restrict__ z,
    const float* __restrict__ wsr,
    const float* __restrict__ Wq, const float* __restrict__ bq,
    const float* __restrict__ bk,
    const float* __restrict__ wv, const float* __restrict__ bv,
    float* __restrict__ out)
{
    __shared__ float lds[16384];

    const int tid  = threadIdx.x;
    const int g    = __builtin_amdgcn_readfirstlane(tid >> 6);
    const int lane = tid & 63;
    const int px16 = lane & 15, py = lane >> 4;
    const int b    = blockIdx.z;
    const int w0   = blockIdx.x * 32 + px16 * 2;
    const int h    = blockIdx.y * 4 + py;
    const int pix  = h * WW + w0;
    const int p0   = py * 32 + px16 * 2;

    const int32x4_t rx = make_srd(x, TOTBYTES);
    const int32x4_t ry = make_srd(y, TOTBYTES);
    const int32x4_t rz = make_srd(z, TOTBYTES);

    const int colb = (w0 > 0 ? w0 - 1 : 0) * 4;
    int rowB[3];
#pragma unroll
    for (int r = 0; r < 3; ++r) {
        const int rr = h - 1 + r;
        rowB[r] = (rr >= 0 && rr < HH) ? rr * WW * 4 + colb : OOB_SENT;
    }
    const bool  intw = (blockIdx.x > 0) & (blockIdx.x < (WW / 32 - 1));
    const float mL = (w0 > 0) ? 1.f : 0.f;
    const float mR = (w0 + 2 < WW) ? 1.f : 0.f;
    const bool  w0e = (w0 == 0);

    const int base = b * CC * HWB;
    const int c0   = __builtin_amdgcn_readfirstlane(g * 8);

    auto mktaps = [&](const floatx4& f, float (&s)[4]) {
        if (intw) { s[0] = f.x; s[1] = f.y; s[2] = f.z; s[3] = f.w; }
        else {
            s[0] = f.x * mL;
            s[1] = w0e ? f.x : f.y;
            s[2] = w0e ? f.y : f.z;
            s[3] = (w0e ? f.z : f.w) * mR;
        }
    };

    floatx2 aP0[8], aP1[8];
#pragma unroll
    for (int i = 0; i < 8; ++i) { aP0[i] = (floatx2){0.f, 0.f}; aP1[i] = (floatx2){0.f, 0.f}; }

    auto load3 = [&](floatx4 (&f)[3], int so) {
#pragma unroll
        for (int r = 0; r < 3; ++r)
            f[r] = llvm_amdgcn_raw_buffer_load_v4f32(rx, rowB[r], so, 0);
    };
    auto compute = [&](const floatx4 (&f)[3], const float* wp) {
        float s[3][4];
#pragma unroll
        for (int r = 0; r < 3; ++r) mktaps(f[r], s[r]);
#pragma unroll
        for (int t = 0; t < 9; ++t) {
            const int tr = t / 3, tc = t % 3;
            const floatx2 t0 = {s[tr][tc],     s[tr][tc]};
            const floatx2 t1 = {s[tr][tc + 1], s[tr][tc + 1]};
#pragma unroll
            for (int j = 0; j < 4; ++j) {
                const floatx4 w4 = *(const floatx4*)&wp[t * 16 + j * 4];
                const floatx2 lo = __builtin_shufflevector(w4, w4, 0, 1);
                const floatx2 hi = __builtin_shufflevector(w4, w4, 2, 3);
                aP0[2 * j + 0] = __builtin_elementwise_fma(lo, t0, aP0[2 * j + 0]);
                aP0[2 * j + 1] = __builtin_elementwise_fma(hi, t0, aP0[2 * j + 1]);
                aP1[2 * j + 0] = __builtin_elementwise_fma(lo, t1, aP1[2 * j + 0]);
                aP1[2 * j + 1] = __builtin_elementwise_fma(hi, t1, aP1[2 * j + 1]);
            }
        }
    };

    {
        floatx4 f0[3], f1[3];
        load3(f0, base + c0 * HWB);
#pragma unroll
        for (int cp = 0; cp < 4; ++cp) {
            load3(f1, base + (c0 + 2 * cp + 1) * HWB);
            compute(f0, wsr + (c0 + 2 * cp) * 144);
            load3(f0, base + (c0 + 2 * cp + 2) * HWB);
            compute(f1, wsr + (c0 + 2 * cp + 1) * 144);
        }
    }

#pragma unroll
    for (int i = 0; i < 8; ++i) {
        *(floatx2*)&lds[g * 2048 + (2 * i + 0) * 128 + p0] = (floatx2){aP0[i].x, aP1[i].x};
        *(floatx2*)&lds[g * 2048 + (2 * i + 1) * 128 + p0] = (floatx2){aP0[i].y, aP1[i].y};
    }
    __syncthreads();

#pragma unroll
    for (int rep = 0; rep < 4; ++rep) {
        const int idx = tid + rep * 512;
        float s = lds[idx];
#pragma unroll
        for (int gg = 1; gg < 8; ++gg) s += lds[gg * 2048 + idx];
        const int d = idx >> 7;
        lds[idx] = fmaxf(s + bk[d], 0.f) * KLOG2E;
    }
    __syncthreads();

    floatx2 kl2[16];
#pragma unroll
    for (int d = 0; d < KD; ++d)
        kl2[d] = *(const floatx2*)&lds[d * 128 + p0];

    auto process = [&](const floatx4 (&f)[3], floatx2 z2, int c) {
        const float* wq = Wq + c * 9;
        float s[3][4];
#pragma unroll
        for (int r = 0; r < 3; ++r) mktaps(f[r], s[r]);
        floatx2 q2 = {bq[c], bq[c]};
#pragma unroll
        for (int t = 0; t < 9; ++t) {
            const int tr = t / 3, tc = t % 3;
            const floatx2 tp2 = {s[tr][tc], s[tr][tc + 1]};
            const floatx2 wq2 = {wq[t], wq[t]};
            q2 = __builtin_elementwise_fma(wq2, tp2, q2);
        }
        const floatx2 zero2 = {0.f, 0.f};
        q2 = __builtin_elementwise_max(q2, zero2);

        floatx2 num2 = zero2, den2 = zero2;
#pragma unroll
        for (int d = 0; d < KD; ++d) {
            const floatx2 s2 = q2 * kl2[d];
            floatx2 e2;
            e2.x = FAST_EXP2(s2.x);
            e2.y = FAST_EXP2(s2.y);
            const floatx2 wv2 = {wv[d], wv[d]};
            const floatx2 bv2 = {bv[d], bv[d]};
            const floatx2 v2 = __builtin_elementwise_max(
                __builtin_elementwise_fma(z2, wv2, bv2), zero2);
            num2 = __builtin_elementwise_fma(e2, v2, num2);
            den2 = den2 + e2;
        }
        floatx2 o2;
        o2.x = __fdividef(num2.x, den2.x);
        o2.y = __fdividef(num2.y, den2.y);
        *(floatx2*)&out[(size_t)b * CC * HW + (size_t)c * HW + pix] = o2;
    };

    auto load3y = [&](floatx4 (&f)[3], floatx2& zz, int so) {
#pragma unroll
        for (int r = 0; r < 3; ++r)
            f[r] = llvm_amdgcn_raw_buffer_load_v4f32(ry, rowB[r], so, 0);
        zz = llvm_amdgcn_raw_buffer_load_v2f32(rz, pix * 4, so, 0);
    };

    {
        floatx4 fy0[3], fy1[3];
        floatx2 z0, z1;
        load3y(fy0, z0, base + c0 * HWB);
#pragma unroll
        for (int cp = 0; cp < 4; ++cp) {
            load3y(fy1, z1, base + (c0 + 2 * cp + 1) * HWB);
            process(fy0, z0, c0 + 2 * cp);
            load3y(fy0, z0, base + (c0 + 2 * cp + 2) * HWB);
            process(fy1, z1, c0 + 2 * cp + 1);
        }
    }
}

extern "C" void kernel_launch(void* const* d_in, const int* in_sizes, int n_in,
                              void* d_out, int out_size, void* d_ws, size_t ws_size,
                              hipStream_t stream) {
    const float* x  = (const float*)d_in[0];
    const float* y  = (const float*)d_in[1];
    const float* z  = (const float*)d_in[2];
    const float* Wq = (const float*)d_in[3];
    const float* bq = (const float*)d_in[4];
    const float* Wk = (const float*)d_in[5];
    const float* bk = (const float*)d_in[6];
    const float* wv = (const float*)d_in[7];
    const float* bv = (const float*)d_in[8];
    float* out = (float*)d_out;

    float* wsr  = (float*)d_ws;                            // 36 KB
    float* kout = (float*)((char*)d_ws + 65536);           // 4 MB
    const size_t need = 65536 + (size_t)4 * KD * HW * 4;   // ~4.26 MB

    hipLaunchKernelGGL(repack_wk, dim3(18), dim3(512), 0, stream, Wk, wsr);

    if (ws_size >= need) {
        // split path: k-conv at 32 waves/CU, then barrier-free attention
        hipLaunchKernelGGL(kconv, dim3(WW / 16, HH / 4, 4), dim3(512), 0, stream,
                           x, wsr, bk, kout);
        hipLaunchKernelGGL(attn, dim3(WW / 32, HH / 4, 4), dim3(512), 0, stream,
                           y, z, kout, Wq, bq, wv, bv, out);
    } else {
        hipLaunchKernelGGL(gatev_fused, dim3(WW / 32, HH / 4, 4), dim3(512), 0, stream,
                           x, y, z, wsr, Wq, bq, bk, wv, bv, out);
    }
}

// Round 17
// 43.259 us; speedup vs baseline: 1.1566x; 1.1566x over previous
//
#include <hip/hip_runtime.h>

#define HH 128
#define WW 128
#define CC 64
#define KD 16
#define HW (HH * WW)
#define HWB (HW * 4)
#define TOTBYTES (4u * CC * HW * 4u)   // B=4 * C=64 * H*W * 4B = 16.78 MB
#define OOB_SENT 0x40000000            // always-OOB voffset -> HW returns 0

typedef __attribute__((ext_vector_type(4))) int   int32x4_t;
typedef __attribute__((ext_vector_type(4))) float floatx4;
typedef __attribute__((ext_vector_type(2))) float floatx2;

__device__ floatx4 llvm_amdgcn_raw_buffer_load_v4f32(int32x4_t srsrc, int voffset,
                                                     int soffset, int aux)
    __asm("llvm.amdgcn.raw.buffer.load.v4f32");
__device__ floatx2 llvm_amdgcn_raw_buffer_load_v2f32(int32x4_t srsrc, int voffset,
                                                     int soffset, int aux)
    __asm("llvm.amdgcn.raw.buffer.load.v2f32");

__device__ inline int32x4_t make_srd(const void* p, unsigned bytes) {
    const unsigned long long a = (unsigned long long)p;
    int32x4_t r;
    r.x = (int)(a & 0xffffffffull);
    r.y = (int)(a >> 32);
    r.z = (int)bytes;
    r.w = 0x00020000;
    return r;
}

#if __has_builtin(__builtin_amdgcn_exp2f)
#define FAST_EXP2(x) __builtin_amdgcn_exp2f(x)
#define KLOG2E 1.44269504088896340736f
#else
#define FAST_EXP2(x) __expf(x)
#define KLOG2E 1.0f
#endif

// R9 configuration — measured best (43.6 us). Block: 512 threads = 8 waves
// over one 32(w) x 4(h) pixel tile; each lane owns a horizontal pixel pair
// (one dwordx4 row-load feeds the 3x3 taps of both pixels; each uniform
// weight ds_read_b128 is amortized over 2 pixels).
// Phase 0: stage Wk -> LDS [cg][ci][t][d16] (conflict-free (d,c) ownership).
// Phase 1: wave g: channels [8g,8g+8) of x, 16 d as 8 d-pair floatx2 accs
//          per pixel (v_pk_fma_f32); partials [g][d][p128] -> 8-way reduce.
// Phase 2: q-conv + v + softmax packed over the pixel pair.
// LDS 64 KB -> 2 blocks/CU (grid = 512 = exactly 2/CU), 16 waves/CU.
__global__ __launch_bounds__(512, 4) void gatev_fused(
    const float* __restrict__ x, const float* __restrict__ y,
    const float* __restrict__ z,
    const float* __restrict__ Wq, const float* __restrict__ bq,
    const float* __restrict__ Wk, const float* __restrict__ bk,
    const float* __restrict__ wv, const float* __restrict__ bv,
    float* __restrict__ out)
{
    __shared__ float lds[16384];   // 64 KB: Wk(36KB) -> partials(64KB) -> k(8KB)

    const int tid  = threadIdx.x;
    const int g    = __builtin_amdgcn_readfirstlane(tid >> 6);
    const int lane = tid & 63;
    const int px16 = lane & 15, py = lane >> 4;
    const int b    = blockIdx.z;
    const int w0   = blockIdx.x * 32 + px16 * 2;   // even
    const int h    = blockIdx.y * 4 + py;
    const int pix  = h * WW + w0;
    const int p0   = py * 32 + px16 * 2;           // pixel-linear in tile

    const int32x4_t rx = make_srd(x, TOTBYTES);
    const int32x4_t ry = make_srd(y, TOTBYTES);
    const int32x4_t rz = make_srd(z, TOTBYTES);

    // One float4 per tap-row at col max(w0-1,0): covers cols w0-1..w0+2,
    // i.e. all taps of the pixel pair.
    const int colb = (w0 > 0 ? w0 - 1 : 0) * 4;
    int rowB[3];
#pragma unroll
    for (int r = 0; r < 3; ++r) {
        const int rr = h - 1 + r;
        rowB[r] = (rr >= 0 && rr < HH) ? rr * WW * 4 + colb : OOB_SENT;
    }
    const float mL = (w0 > 0) ? 1.f : 0.f;           // px0 left tap
    const float mR = (w0 + 2 < WW) ? 1.f : 0.f;      // px1 right tap
    const bool  w0e = (w0 == 0);

    const int base = b * CC * HWB;
    const int c0   = __builtin_amdgcn_readfirstlane(g * 8);

    // ---------------- phase 0: stage Wk -> LDS [cg][ci][t][d16] -------------
    {
        const int d  = tid & 15;
        const int cA = tid >> 4;           // [0,32)
#pragma unroll
        for (int half = 0; half < 2; ++half) {
            const int c   = cA + half * 32;
            const int dst = (c >> 3) * 1152 + (c & 7) * 144 + d;
            const float* src = Wk + (d * CC + c) * 9;
#pragma unroll
            for (int t = 0; t < 9; ++t)
                lds[dst + t * 16] = src[t];
        }
    }
    __syncthreads();

    // ---------------- phase 1: packed partial k, 8 channels, 2 px ----------
    floatx2 aP0[8], aP1[8];                // [d-pair] per pixel
#pragma unroll
    for (int i = 0; i < 8; ++i) { aP0[i] = (floatx2){0.f, 0.f}; aP1[i] = (floatx2){0.f, 0.f}; }

    auto load3 = [&](floatx4 (&f)[3], int so) {
#pragma unroll
        for (int r = 0; r < 3; ++r)
            f[r] = llvm_amdgcn_raw_buffer_load_v4f32(rx, rowB[r], so, 0);
    };
    // 4 tap columns per row: s0 = w0-1 (masked), s1 = w0, s2 = w0+1, s3 = w0+2 (masked)
    auto mktaps = [&](const floatx4& f, float (&s)[4]) {
        s[0] = f.x * mL;
        s[1] = w0e ? f.x : f.y;
        s[2] = w0e ? f.y : f.z;
        s[3] = (w0e ? f.z : f.w) * mR;
    };
    auto compute = [&](const floatx4 (&f)[3], int wb) {
        float s[3][4];
#pragma unroll
        for (int r = 0; r < 3; ++r) mktaps(f[r], s[r]);
#pragma unroll
        for (int t = 0; t < 9; ++t) {
            const int tr = t / 3, tc = t % 3;
            const floatx2 t0 = {s[tr][tc],     s[tr][tc]};
            const floatx2 t1 = {s[tr][tc + 1], s[tr][tc + 1]};
#pragma unroll
            for (int j = 0; j < 4; ++j) {    // uniform ds_read_b128
                const floatx4 w4 = *(const floatx4*)&lds[wb + t * 16 + j * 4];
                const floatx2 lo = __builtin_shufflevector(w4, w4, 0, 1);
                const floatx2 hi = __builtin_shufflevector(w4, w4, 2, 3);
                aP0[2 * j + 0] = __builtin_elementwise_fma(lo, t0, aP0[2 * j + 0]);
                aP0[2 * j + 1] = __builtin_elementwise_fma(hi, t0, aP0[2 * j + 1]);
                aP1[2 * j + 0] = __builtin_elementwise_fma(lo, t1, aP1[2 * j + 0]);
                aP1[2 * j + 1] = __builtin_elementwise_fma(hi, t1, aP1[2 * j + 1]);
            }
        }
    };

    const int wbase = g * 1152;
    floatx4 f0[3], f1[3];
    load3(f0, base + c0 * HWB);
#pragma unroll
    for (int cp = 0; cp < 4; ++cp) {
        load3(f1, base + (c0 + 2 * cp + 1) * HWB);       // prefetch odd channel
        compute(f0, wbase + (2 * cp) * 144);
        load3(f0, base + (c0 + 2 * cp + 2) * HWB);       // prefetch next even (tail SRD-bounded)
        compute(f1, wbase + (2 * cp + 1) * 144);
    }
    __syncthreads();                                     // weight reads done

    // partials [g][d][p]: (p0, p0+1) contiguous -> b64 writes
#pragma unroll
    for (int i = 0; i < 8; ++i) {
        *(floatx2*)&lds[g * 2048 + (2 * i + 0) * 128 + p0] = (floatx2){aP0[i].x, aP1[i].x};
        *(floatx2*)&lds[g * 2048 + (2 * i + 1) * 128 + p0] = (floatx2){aP0[i].y, aP1[i].y};
    }
    __syncthreads();

    // ---------------- reduce 8 partials -> k[d][p] (in place) ---------------
#pragma unroll
    for (int rep = 0; rep < 4; ++rep) {
        const int idx = tid + rep * 512;                 // = d*128 + p
        float s = lds[idx];
#pragma unroll
        for (int gg = 1; gg < 8; ++gg) s += lds[gg * 2048 + idx];
        const int d = idx >> 7;                          // wave-uniform
        lds[idx] = fmaxf(s + bk[d], 0.f) * KLOG2E;
    }
    __syncthreads();

    // ---------------- phase 2: q, v, softmax, packed over pixel pair --------
    floatx2 kl2[16];                                     // k for both pixels, hoisted
#pragma unroll
    for (int d = 0; d < KD; ++d)
        kl2[d] = *(const floatx2*)&lds[d * 128 + p0];

    auto process = [&](const floatx4 (&f)[3], floatx2 z2, int c) {
        const float* wq = Wq + c * 9;                    // uniform -> s_load
        float s[3][4];
#pragma unroll
        for (int r = 0; r < 3; ++r) mktaps(f[r], s[r]);
        floatx2 q2 = {bq[c], bq[c]};
#pragma unroll
        for (int t = 0; t < 9; ++t) {
            const int tr = t / 3, tc = t % 3;
            const floatx2 tp2 = {s[tr][tc], s[tr][tc + 1]};
            const floatx2 wq2 = {wq[t], wq[t]};
            q2 = __builtin_elementwise_fma(wq2, tp2, q2);
        }
        const floatx2 zero2 = {0.f, 0.f};
        q2 = __builtin_elementwise_max(q2, zero2);

        floatx2 num2 = zero2, den2 = zero2;
#pragma unroll
        for (int d = 0; d < KD; ++d) {
            const floatx2 s2 = q2 * kl2[d];              // v_pk_mul_f32
            floatx2 e2;
            e2.x = FAST_EXP2(s2.x);
            e2.y = FAST_EXP2(s2.y);
            const floatx2 wv2 = {wv[d], wv[d]};
            const floatx2 bv2 = {bv[d], bv[d]};
            const floatx2 v2 = __builtin_elementwise_max(
                __builtin_elementwise_fma(z2, wv2, bv2), zero2);
            num2 = __builtin_elementwise_fma(e2, v2, num2);
            den2 = den2 + e2;
        }
        floatx2 o2;
        o2.x = __fdividef(num2.x, den2.x);
        o2.y = __fdividef(num2.y, den2.y);
        *(floatx2*)&out[(size_t)b * CC * HW + (size_t)c * HW + pix] = o2;
    };

    floatx4 fy0[3], fy1[3];
    floatx2 z0, z1;
    auto load3y = [&](floatx4 (&f)[3], floatx2& zz, int so) {
#pragma unroll
        for (int r = 0; r < 3; ++r)
            f[r] = llvm_amdgcn_raw_buffer_load_v4f32(ry, rowB[r], so, 0);
        zz = llvm_amdgcn_raw_buffer_load_v2f32(rz, pix * 4, so, 0);
    };

    load3y(fy0, z0, base + c0 * HWB);
#pragma unroll
    for (int cp = 0; cp < 4; ++cp) {
        load3y(fy1, z1, base + (c0 + 2 * cp + 1) * HWB);
        process(fy0, z0, c0 + 2 * cp);
        load3y(fy0, z0, base + (c0 + 2 * cp + 2) * HWB); // tail SRD-bounded
        process(fy1, z1, c0 + 2 * cp + 1);
    }
}

extern "C" void kernel_launch(void* const* d_in, const int* in_sizes, int n_in,
                              void* d_out, int out_size, void* d_ws, size_t ws_size,
                              hipStream_t stream) {
    const float* x  = (const float*)d_in[0];
    const float* y  = (const float*)d_in[1];
    const float* z  = (const float*)d_in[2];
    const float* Wq = (const float*)d_in[3];
    const float* bq = (const float*)d_in[4];
    const float* Wk = (const float*)d_in[5];
    const float* bk = (const float*)d_in[6];
    const float* wv = (const float*)d_in[7];
    const float* bv = (const float*)d_in[8];
    float* out = (float*)d_out;

    dim3 grid(WW / 32, HH / 4, 4);   // (4, 32, 4) = 512 blocks = 2/CU
    dim3 block(512);                 // 8 waves
    hipLaunchKernelGGL(gatev_fused, grid, block, 0, stream,
                       x, y, z, Wq, bq, Wk, bk, wv, bv, out);
}